// Round 9
// baseline (122.691 us; speedup 1.0000x reference)
//
#include <hip/hip_runtime.h>
#include <stdint.h>
#include <utility>

// PostProcessor3D: threshold(>0.9) + 5x5x5 stride-1 maxpool + strict-local-max
// mask on [64,512,512] fp32.
//
// R20: OCCUPANCY -> PIPE OVERLAP. R19 post-mortem: request-byte model
// falsified (FETCH hit the 65.5 MB minimum, dur unchanged). What fits all
// nine rounds: per-CU demands {VMEM ~28us, VALU ~10us, LDS ~7.5us} SUM to
// the measured ~45us -- the pipes run serially per slice. Overlapped max
// would be ~21-28us. Occupancy trend is monotone (2blk/CU 44.5 > 4blk/CU
// ~41.5; R12's 85%-occ spill storm realized 3.6 TB/s) and has never been
// tested >42% without spills. This round: 6 blocks/CU, 24 waves = 75%.
//  (a) DEPTH 5->4: LDS 24576 B -> floor(160K/24576) = 6 resident blocks.
//      WAR-safe via REORDERED iteration [wait; barrier; stage(t+3);
//      consume(t)]: stage(t+3) writes buf[(t+3)%4] == buf[(t-1)%4], issued
//      AFTER barrier(t); all readers of that buffer (consume(t-1)) consumed
//      their data before barrier(t). No race.
//  (b) DCHUNK=8 -> grid 2048: supplies 8 blocks/CU geometric so LDS's 6
//      can actually be resident (R19's grid 512 capped at 2).
//  (c) vmcnt counts re-derived for the new issue order (per wave):
//      iter j issues [stage(j+3); store(j-4)]. At iter t's wait, ops newer
//      than stage(t): stage groups {t+1,t+2} (la = min(2, NS-1-t)) +
//      stores of iters {t-3,t-2,t-1} with j>=4 (sa). N = (hasB?2:1)*la+sa.
//      Steady state N=5: retires only >=3-slice-old ops, keeps dist-3 lead.
//  (d) Everything else byte-for-byte R19/R16 (proven absmax=0): shared
//      6-chunk staging, raw-max trick, clamp-replicate, H-max direct from
//      LDS + halo column, W-max via 4 shuffles, win[5]/cen[2] rings,
//      plain s_barrier (NO waitcnt drain), nontemporal stores, VGPR<=64.
//
// Tile: W=64 x H=16, DCHUNK=8 -> grid 8 x 32 x 8 = 2048 blocks, 256 thr.

#define THRESH 0.9f

constexpr int D = 64, H = 512, W = 512;
constexpr int HW = H * W;
constexpr int TW = 64;                    // tile width (floats)
constexpr int TH = 16;                    // tile height
constexpr int DCHUNK = 8;                 // depth outputs per block
constexpr int HALO = 2;
constexpr int LROWS = TH + 2 * HALO;      // 20 staged rows
constexpr int RAWQ = TW / 4 + 2;          // 18 quads/row (linear, DMA dest)
constexpr int NQ = LROWS * RAWQ;          // 360 real quads
constexpr int SLOTS = 384;                // 6 chunks x 64 lanes
constexpr int DEPTH = 4;                  // LDS ring depth (stage-after-barrier)
constexpr int NS = DCHUNK + 2 * HALO;     // 12 slices per block

typedef float floatx4 __attribute__((ext_vector_type(4)));
using gu32p = const __attribute__((address_space(1))) uint32_t*;
using lu32p = __attribute__((address_space(3))) uint32_t*;

__device__ __forceinline__ float4 max4(float4 a, float4 b) {
    return make_float4(fmaxf(a.x, b.x), fmaxf(a.y, b.y),
                       fmaxf(a.z, b.z), fmaxf(a.w, b.w));
}

// 5-tap sliding max for one quad. b = own (f4..f7), f2,f3 = left neighbor's
// .z,.w; f8,f9 = right neighbor's .x,.y. out[j] = max over [4c+j-2, 4c+j+2].
__device__ __forceinline__ float4 wmax5s(float f2, float f3, float4 b,
                                         float f8, float f9) {
    const float f4 = b.x, f5 = b.y, f6 = b.z, f7 = b.w;
    const float m45 = fmaxf(f4, f5);
    const float m56 = fmaxf(f5, f6);
    const float m345 = fmaxf(f3, m45);
    const float m456 = fmaxf(f4, m56);
    const float m567 = fmaxf(m56, f7);
    const float m678 = fmaxf(fmaxf(f6, f7), f8);
    float4 r;
    r.x = fmaxf(fmaxf(f2, f6), m345);
    r.y = fmaxf(fmaxf(f3, f7), m456);
    r.z = fmaxf(fmaxf(f4, f8), m567);
    r.w = fmaxf(fmaxf(f5, f9), m678);
    return r;
}

template <int N>
__device__ __forceinline__ void cwait() {   // counted vmcnt, no lgkm/exp wait
    asm volatile("s_waitcnt vmcnt(%0)" :: "n"(N) : "memory");
}

template <typename F, int... I>
__device__ __forceinline__ void static_for_impl(F&& f,
                                                std::integer_sequence<int, I...>) {
    (f(std::integral_constant<int, I>{}), ...);
}
template <int N, typename F>
__device__ __forceinline__ void static_for(F&& f) {
    static_for_impl(static_cast<F&&>(f), std::make_integer_sequence<int, N>{});
}

__global__ __launch_bounds__(256)
__attribute__((amdgpu_num_vgpr(64)))
void peak3d_kernel(const float* __restrict__ in, float* __restrict__ out) {
    __shared__ float4 raw[DEPTH][SLOTS];  // 4 x 6144 B = 24576 B

    const int tid = threadIdx.y * 16 + threadIdx.x;
    const int wid = tid >> 6;             // wave 0..3
    const int lane = tid & 63;
    const int tx = tid & 15;              // quad col 0..15
    const int ty = tid >> 4;              // row 0..15

    const int w0 = blockIdx.x * TW;
    const int h0 = blockIdx.y * TH;
    const int d0 = blockIdx.z * DCHUNK;

    // Staging: chunk A = wid (all waves), chunk B = 4+wid (waves 0,1 only).
    // Slot s -> (row, col) = (s/18, s%18); trash slots (>=360) clamp source.
    const bool hasB = (wid < 2);
    const int sA = min(64 * wid + lane, NQ - 1);
    const int sB = min(64 * (4 + wid) + lane, NQ - 1);
    const int rA = sA / RAWQ, cA = sA % RAWQ;
    const int rB = sB / RAWQ, cB = sB % RAWQ;
    const int ghA = min(max(h0 + rA - HALO, 0), H - 1);   // clamp-replicate
    const int gwA = min(max(w0 + 4 * cA - 4, 0), W - 4);
    const int ghB = min(max(h0 + rB - HALO, 0), H - 1);
    const int gwB = min(max(w0 + 4 * cB - 4, 0), W - 4);
    const int offA = ghA * W + gwA;
    const int offB = ghB * W + gwB;

    // Consume-phase indices (R13/R16/R19 proven).
    const int rbase = ty * RAWQ + tx + 1;          // + rr*RAWQ, rr=0..4
    const bool isL = (tx == 0), isR = (tx == 15);
    const bool edgeW = (isL && w0 == 0) || (isR && w0 == W - TW);
    const int hbase = (ty * RAWQ + (isL ? 0 : RAWQ - 1)) * 2 + (isL ? 1 : 0);

    const float4 zero4 = make_float4(0.f, 0.f, 0.f, 0.f);
    float4 win[5];                        // HW-max ring, depth 5 (D window)
    float4 cen[2];                        // raw center ring, depth 2
#pragma unroll
    for (int k = 0; k < 5; ++k) win[k] = zero4;
    cen[0] = zero4; cen[1] = zero4;

    // Issue DMA for slice t into raw[t % DEPTH]. Wave-uniform LDS base.
    auto stage = [&](int t) {
        const int dd = min(max(d0 - HALO + t, 0), D - 1);
        const float* sp = in + dd * HW;
        float4* ldsb = &raw[t % DEPTH][0];
        __builtin_amdgcn_global_load_lds((gu32p)(sp + offA),
                                         (lu32p)(ldsb + 64 * wid), 16, 0, 0);
        if (hasB)
            __builtin_amdgcn_global_load_lds((gu32p)(sp + offB),
                                             (lu32p)(ldsb + 64 * (4 + wid)),
                                             16, 0, 0);
    };

    // Prologue: 3 slices in flight (dist-3).
    stage(0); stage(1); stage(2);

    static_for<NS>([&](auto tc) {
        constexpr int t = decltype(tc)::value;

        // ---- counted wait (BEFORE barrier): retire stage(t) ----
        // Ops newer than stage(t) in issue order [.. stage(j+3); store(j-4)..]:
        //   stage groups t+1, t+2 (if < NS), each 2 ops (hasB) or 1;
        //   stores of iters {t-3, t-2, t-1} with j >= 4.
        constexpr int laA = (NS - 1 - t < 0) ? 0 : (NS - 1 - t);
        constexpr int la = (laA < 2) ? laA : 2;
        constexpr int jlo = (t - 3 > 4) ? (t - 3) : 4;
        constexpr int sa = (t - 1 >= jlo) ? (t - 1 - jlo + 1) : 0;
        if (hasB) cwait<2 * la + sa>(); else cwait<la + sa>();
        asm volatile("s_barrier" ::: "memory");

        // ---- stage AFTER barrier: DEPTH-4 WAR-safe (readers of the
        //      overwritten buffer all passed barrier(t) already) ----
        if (t + 3 < NS) stage(t + 3);     // keep 3 slices ahead

        // ---- consume: H-max (5 rows) from LDS ring ----
        const float4* bp = &raw[t % DEPTH][0];
        const float4 r0q = bp[rbase + 0 * RAWQ];
        const float4 r1q = bp[rbase + 1 * RAWQ];
        const float4 r2q = bp[rbase + 2 * RAWQ];   // center row (raw)
        const float4 r3q = bp[rbase + 3 * RAWQ];
        const float4 r4q = bp[rbase + 4 * RAWQ];
        const float4 hv = max4(max4(max4(r0q, r1q), max4(r3q, r4q)), r2q);

        // ---- halo H-max: edge lanes only ----
        float2 h = make_float2(0.f, 0.f);
        if (isL || isR) {
            const float2* hp = reinterpret_cast<const float2*>(bp);
            const float2 e0 = hp[hbase + 0 * RAWQ * 2];
            const float2 e1 = hp[hbase + 1 * RAWQ * 2];
            const float2 e2 = hp[hbase + 2 * RAWQ * 2];
            const float2 e3 = hp[hbase + 3 * RAWQ * 2];
            const float2 e4 = hp[hbase + 4 * RAWQ * 2];
            h.x = fmaxf(fmaxf(fmaxf(e0.x, e1.x), fmaxf(e3.x, e4.x)), e2.x);
            h.y = fmaxf(fmaxf(fmaxf(e0.y, e1.y), fmaxf(e3.y, e4.y)), e2.y);
            if (edgeW) { h.x = 0.f; h.y = 0.f; }   // true OOB in W: pad 0
        }

        // ---- W-max via shuffles on H-maxed quads ----
        float f2 = __shfl_up(hv.z, 1);
        float f3 = __shfl_up(hv.w, 1);
        float f8 = __shfl_down(hv.x, 1);
        float f9 = __shfl_down(hv.y, 1);
        if (isL) { f2 = h.x; f3 = h.y; }
        if (isR) { f8 = h.x; f9 = h.y; }

        win[t % 5] = wmax5s(f2, f3, hv, f8, f9);   // HW-max, slice t

        // ---- D-max + strict-local-max + store (center = slice t-2) ----
        if (t >= 4) {
            const int dout = d0 + (t - 4);
            const float4 mp = max4(max4(max4(win[0], win[1]),
                                        max4(win[2], win[3])), win[4]);
            const float4 c = cen[t & 1];           // written at iter t-2
            floatx4 res;
            res.x = (c.x > THRESH && mp.x == c.x) ? c.x : 0.f;
            res.y = (c.y > THRESH && mp.y == c.y) ? c.y : 0.f;
            res.z = (c.z > THRESH && mp.z == c.z) ? c.z : 0.f;
            res.w = (c.w > THRESH && mp.w == c.w) ? c.w : 0.f;
            floatx4* op = reinterpret_cast<floatx4*>(
                out + (size_t)(dout * HW + (h0 + ty) * W + (w0 + 4 * tx)));
            __builtin_nontemporal_store(res, op);
        }
        cen[t & 1] = r2q;                          // write AFTER read above
    });
}

extern "C" void kernel_launch(void* const* d_in, const int* in_sizes, int n_in,
                              void* d_out, int out_size, void* d_ws, size_t ws_size,
                              hipStream_t stream) {
    const float* in = (const float*)d_in[0];
    float* out = (float*)d_out;
    dim3 grid(W / TW, H / TH, D / DCHUNK);    // 8 x 32 x 8 = 2048 blocks
    dim3 block(16, 16, 1);
    hipLaunchKernelGGL(peak3d_kernel, grid, block, 0, stream, in, out);
}

// Round 10
// 120.713 us; speedup vs baseline: 1.0164x; 1.0164x over previous
//
#include <hip/hip_runtime.h>
#include <stdint.h>
#include <utility>

// PostProcessor3D: threshold(>0.9) + 5x5x5 stride-1 maxpool + strict-local-max
// mask on [64,512,512] fp32.
//
// R21: AMORTIZE THE PER-WAVE-SLICE FIXED COST (vertical pairing).
// Ten-round dataset: every structure costs 1140-1480 CU-cyc per block-slice
// (64x16 tile per z-step) regardless of sync scheme, prefetch depth,
// LDS/no-LDS, occupancy (19-85%), or traffic (R19 hit the 65.5 MB FETCH
// floor with no speedup). Cost tracks the NUMBER of wave-slice iterations,
// not bytes and not any pipe counter -> fixed per-iteration cost (barrier
// join + ds_read latency + fold chain + issue overhead). Untested axis:
// work per iteration. This round each lane owns TWO output rows (ty, ty+16):
// block = 64x32 tile, half the iterations per volume.
//  (a) R16 skeleton byte-for-byte where proven: DEPTH-5 LDS ring, dist-3
//      DMA prefetch, stage(t+3) -> counted vmcnt -> s_barrier -> consume,
//      raw-max trick, clamp-replicate, halo column reads, 4-shuffle W-max,
//      win[5]/cen[2] rings per pipe, nontemporal stores.
//  (b) Staged rows 36 (= 32 + 2*HALO): H-halo redundancy 1.125x (was 1.25).
//      704 slots = 11 x 64-lane DMA groups: waves 0-2 issue 3 groups, wave 3
//      issues 2 (hasC wave-uniform) -> vmcnt counts per-wave uniform.
//  (c) Stores per iter = 2 -> store term in vmcnt algebra doubled
//      (re-derived; validated at t = 0,1,4,5,17,18,19).
//  (d) NO VGPR cap: occupancy is grid-bound (512 blocks = 2/CU) no matter
//      what the allocator picks -> the R12 cap-induced-spill trap is gone.
//      Rings ~112 regs + temps fit well under 256.
//
// Tile: W=64 x H=32, DCHUNK=16 -> grid 8 x 16 x 4 = 512 blocks, 256 thr.

#define THRESH 0.9f

constexpr int D = 64, H = 512, W = 512;
constexpr int HW = H * W;
constexpr int TW = 64;                    // tile width (floats)
constexpr int TH = 32;                    // tile height (2 rows per lane)
constexpr int DCHUNK = 16;                // depth outputs per block
constexpr int HALO = 2;
constexpr int LROWS = TH + 2 * HALO;      // 36 staged rows
constexpr int RAWQ = TW / 4 + 2;          // 18 quads/row (linear, DMA dest)
constexpr int NQ = LROWS * RAWQ;          // 648 real quads
constexpr int SLOTS = 704;                // 11 groups x 64 lanes
constexpr int DEPTH = 5;                  // LDS ring depth (dist-3 + WAR)
constexpr int NS = DCHUNK + 2 * HALO;     // 20 slices per block

typedef float floatx4 __attribute__((ext_vector_type(4)));
using gu32p = const __attribute__((address_space(1))) uint32_t*;
using lu32p = __attribute__((address_space(3))) uint32_t*;

__device__ __forceinline__ float4 max4(float4 a, float4 b) {
    return make_float4(fmaxf(a.x, b.x), fmaxf(a.y, b.y),
                       fmaxf(a.z, b.z), fmaxf(a.w, b.w));
}

// 5-tap sliding max for one quad. b = own (f4..f7), f2,f3 = left neighbor's
// .z,.w; f8,f9 = right neighbor's .x,.y. out[j] = max over [4c+j-2, 4c+j+2].
__device__ __forceinline__ float4 wmax5s(float f2, float f3, float4 b,
                                         float f8, float f9) {
    const float f4 = b.x, f5 = b.y, f6 = b.z, f7 = b.w;
    const float m45 = fmaxf(f4, f5);
    const float m56 = fmaxf(f5, f6);
    const float m345 = fmaxf(f3, m45);
    const float m456 = fmaxf(f4, m56);
    const float m567 = fmaxf(m56, f7);
    const float m678 = fmaxf(fmaxf(f6, f7), f8);
    float4 r;
    r.x = fmaxf(fmaxf(f2, f6), m345);
    r.y = fmaxf(fmaxf(f3, f7), m456);
    r.z = fmaxf(fmaxf(f4, f8), m567);
    r.w = fmaxf(fmaxf(f5, f9), m678);
    return r;
}

template <int N>
__device__ __forceinline__ void cwait() {   // counted vmcnt, no lgkm/exp wait
    asm volatile("s_waitcnt vmcnt(%0)" :: "n"(N) : "memory");
}

template <typename F, int... I>
__device__ __forceinline__ void static_for_impl(F&& f,
                                                std::integer_sequence<int, I...>) {
    (f(std::integral_constant<int, I>{}), ...);
}
template <int N, typename F>
__device__ __forceinline__ void static_for(F&& f) {
    static_for_impl(static_cast<F&&>(f), std::make_integer_sequence<int, N>{});
}

__global__ __launch_bounds__(256)
void peak3d_kernel(const float* __restrict__ in, float* __restrict__ out) {
    __shared__ float4 raw[DEPTH][SLOTS];  // 5 x 11264 B = 56320 B

    const int tid = threadIdx.y * 16 + threadIdx.x;
    const int wid = tid >> 6;             // wave 0..3
    const int tx = tid & 15;              // quad col 0..15
    const int ty = tid >> 4;              // row 0..15 (pipe A); +16 = pipe B

    const int w0 = blockIdx.x * TW;
    const int h0 = blockIdx.y * TH;
    const int d0 = blockIdx.z * DCHUNK;

    // Staging: 3 slots per lane at tid, tid+256, tid+512 (third only for
    // waves 0-2: slots 512..703). Trash slots (>=648) clamp to slot 647.
    const bool hasC = (wid < 3);
    int offs[3];
#pragma unroll
    for (int i = 0; i < 3; ++i) {
        const int s = min(tid + 256 * i, NQ - 1);
        const int r = s / RAWQ, c = s % RAWQ;
        const int gh = min(max(h0 + r - HALO, 0), H - 1);   // clamp-replicate
        const int gw = min(max(w0 + 4 * c - 4, 0), W - 4);
        offs[i] = gh * W + gw;
    }
    const int off0 = offs[0], off1 = offs[1], off2 = offs[2];

    // Consume-phase indices, per pipe (A: row ty; B: row ty+16).
    const bool isL = (tx == 0), isR = (tx == 15);
    const bool edgeW = (isL && w0 == 0) || (isR && w0 == W - TW);
    const int rbaseA = ty * RAWQ + tx + 1;                 // + rr*RAWQ
    const int rbaseB = (ty + 16) * RAWQ + tx + 1;
    const int hcolq = isL ? 0 : (RAWQ - 1);
    const int hbaseA = (ty * RAWQ + hcolq) * 2 + (isL ? 1 : 0);
    const int hbaseB = ((ty + 16) * RAWQ + hcolq) * 2 + (isL ? 1 : 0);

    const float4 zero4 = make_float4(0.f, 0.f, 0.f, 0.f);
    float4 winA[5], winB[5];              // HW-max rings (D window)
    float4 cenA[2], cenB[2];              // raw center rings
#pragma unroll
    for (int k = 0; k < 5; ++k) { winA[k] = zero4; winB[k] = zero4; }
    cenA[0] = zero4; cenA[1] = zero4; cenB[0] = zero4; cenB[1] = zero4;

    // Issue DMA for slice t into raw[t % DEPTH]. Wave-uniform LDS bases.
    auto stage = [&](int t) {
        const int dd = min(max(d0 - HALO + t, 0), D - 1);
        const float* sp = in + dd * HW;
        float4* ldsb = &raw[t % DEPTH][0];
        __builtin_amdgcn_global_load_lds((gu32p)(sp + off0),
                                         (lu32p)(ldsb + 64 * wid), 16, 0, 0);
        __builtin_amdgcn_global_load_lds((gu32p)(sp + off1),
                                         (lu32p)(ldsb + 256 + 64 * wid), 16, 0, 0);
        if (hasC)
            __builtin_amdgcn_global_load_lds((gu32p)(sp + off2),
                                             (lu32p)(ldsb + 512 + 64 * wid),
                                             16, 0, 0);
    };

    // One pipe's consume for slice t: H-max, halo, W-max, D-max, store.
    auto consume = [&](const float4* bp, int rbase, int hbase, int hrow,
                       float4 (&win)[5], float4 (&cen)[2], auto tcc) {
        constexpr int t = decltype(tcc)::value;

        const float4 r0q = bp[rbase + 0 * RAWQ];
        const float4 r1q = bp[rbase + 1 * RAWQ];
        const float4 r2q = bp[rbase + 2 * RAWQ];   // center row (raw)
        const float4 r3q = bp[rbase + 3 * RAWQ];
        const float4 r4q = bp[rbase + 4 * RAWQ];
        const float4 hv = max4(max4(max4(r0q, r1q), max4(r3q, r4q)), r2q);

        float2 h = make_float2(0.f, 0.f);
        if (isL || isR) {
            const float2* hp = reinterpret_cast<const float2*>(bp);
            const float2 e0 = hp[hbase + 0 * RAWQ * 2];
            const float2 e1 = hp[hbase + 1 * RAWQ * 2];
            const float2 e2 = hp[hbase + 2 * RAWQ * 2];
            const float2 e3 = hp[hbase + 3 * RAWQ * 2];
            const float2 e4 = hp[hbase + 4 * RAWQ * 2];
            h.x = fmaxf(fmaxf(fmaxf(e0.x, e1.x), fmaxf(e3.x, e4.x)), e2.x);
            h.y = fmaxf(fmaxf(fmaxf(e0.y, e1.y), fmaxf(e3.y, e4.y)), e2.y);
            if (edgeW) { h.x = 0.f; h.y = 0.f; }   // true OOB in W: pad 0
        }

        float f2 = __shfl_up(hv.z, 1);
        float f3 = __shfl_up(hv.w, 1);
        float f8 = __shfl_down(hv.x, 1);
        float f9 = __shfl_down(hv.y, 1);
        if (isL) { f2 = h.x; f3 = h.y; }
        if (isR) { f8 = h.x; f9 = h.y; }

        win[t % 5] = wmax5s(f2, f3, hv, f8, f9);   // HW-max, slice t

        if (t >= 4) {
            const int dout = d0 + (t - 4);
            const float4 mp = max4(max4(max4(win[0], win[1]),
                                        max4(win[2], win[3])), win[4]);
            const float4 c = cen[t & 1];           // written at iter t-2
            floatx4 res;
            res.x = (c.x > THRESH && mp.x == c.x) ? c.x : 0.f;
            res.y = (c.y > THRESH && mp.y == c.y) ? c.y : 0.f;
            res.z = (c.z > THRESH && mp.z == c.z) ? c.z : 0.f;
            res.w = (c.w > THRESH && mp.w == c.w) ? c.w : 0.f;
            floatx4* op = reinterpret_cast<floatx4*>(
                out + (size_t)(dout * HW + (h0 + hrow) * W + (w0 + 4 * tx)));
            __builtin_nontemporal_store(res, op);
        }
        cen[t & 1] = r2q;                          // write AFTER read above
    };

    // Prologue: 3 slices in flight (dist-3).
    stage(0); stage(1); stage(2);

    static_for<NS>([&](auto tc) {
        constexpr int t = decltype(tc)::value;

        if (t + 3 < NS) stage(t + 3);     // keep 3 slices ahead

        // ---- counted wait: retire ONLY ops >= 3 iters old ----
        // Newer than stage-group(t): groups t+1..min(t+3,NS-1) (nl ops each)
        // + stores of iters [max(4, t-3), t-1] (2 ops each).
        constexpr int la = (NS - 1 - t < 3) ? (NS - 1 - t) : 3;
        constexpr int lo = (t - 3 > 4) ? (t - 3) : 4;
        constexpr int sa = 2 * ((t - 1 >= lo) ? (t - 1 - lo + 1) : 0);
        if (hasC) cwait<3 * la + sa>(); else cwait<2 * la + sa>();
        asm volatile("s_barrier" ::: "memory");

        const float4* bp = &raw[t % DEPTH][0];
        consume(bp, rbaseA, hbaseA, ty,      winA, cenA, tc);   // rows ty
        consume(bp, rbaseB, hbaseB, ty + 16, winB, cenB, tc);   // rows ty+16
    });
}

extern "C" void kernel_launch(void* const* d_in, const int* in_sizes, int n_in,
                              void* d_out, int out_size, void* d_ws, size_t ws_size,
                              hipStream_t stream) {
    const float* in = (const float*)d_in[0];
    float* out = (float*)d_out;
    dim3 grid(W / TW, H / TH, D / DCHUNK);    // 8 x 16 x 4 = 512 blocks
    dim3 block(16, 16, 1);
    hipLaunchKernelGGL(peak3d_kernel, grid, block, 0, stream, in, out);
}